// Round 1
// baseline (139.361 us; speedup 1.0000x reference)
//
#include <hip/hip_runtime.h>

// NonMaximaSuppression2d: x shape (B=8, C=128, H=256, W=256) fp32.
// out[p] = x[p] if x[p] > max(0, 8 replicate-padded 3x3 neighbors) else 0.
// Note: reference initializes the running max to 0 (center conv channel is
// all-zero), so negative x is always suppressed.

#define NMS_H 256
#define NMS_W 256

__global__ __launch_bounds__(256) void nms2d_kernel(
    const float* __restrict__ x, float* __restrict__ out, int total4) {
    const int idx = blockIdx.x * blockDim.x + threadIdx.x;
    if (idx >= total4) return;

    // Each thread handles 4 consecutive pixels along W.
    const int w4   = idx & (NMS_W / 4 - 1);   // 64 float4-segments per row
    const int row  = idx >> 6;                // global row index (plane-major)
    const int y    = row & (NMS_H - 1);
    const long plane = row >> 8;              // b*C + c

    const float* p = x + plane * (long)(NMS_H * NMS_W);
    // Replicate padding via clamped row/col indices. When y==0 the "above"
    // row aliases row 0, so the (0,1) tap reads the center value itself —
    // this matches the reference's edge-pad semantics exactly.
    const int ym = (y == 0) ? 0 : y - 1;
    const int yp = (y == NMS_H - 1) ? NMS_H - 1 : y + 1;
    const int c0 = w4 * 4;
    const int cl = (c0 == 0) ? 0 : c0 - 1;
    const int cr = (c0 + 4 >= NMS_W) ? NMS_W - 1 : c0 + 4;

    float t[6], m[6], b[6];
    {
        const float* rt = p + (long)ym * NMS_W;
        const float4 v = *reinterpret_cast<const float4*>(rt + c0);
        t[0] = rt[cl]; t[1] = v.x; t[2] = v.y; t[3] = v.z; t[4] = v.w; t[5] = rt[cr];
    }
    {
        const float* rm = p + (long)y * NMS_W;
        const float4 v = *reinterpret_cast<const float4*>(rm + c0);
        m[0] = rm[cl]; m[1] = v.x; m[2] = v.y; m[3] = v.z; m[4] = v.w; m[5] = rm[cr];
    }
    {
        const float* rb = p + (long)yp * NMS_W;
        const float4 v = *reinterpret_cast<const float4*>(rb + c0);
        b[0] = rb[cl]; b[1] = v.x; b[2] = v.y; b[3] = v.z; b[4] = v.w; b[5] = rb[cr];
    }

    float4 o;
    float* op = &o.x;
#pragma unroll
    for (int k = 0; k < 4; ++k) {
        // max over 8 non-center neighbors and implicit 0
        float mx = fmaxf(fmaxf(t[k], t[k + 1]), t[k + 2]);   // top row: 3 taps
        mx = fmaxf(mx, fmaxf(m[k], m[k + 2]));               // mid row: skip center
        mx = fmaxf(mx, fmaxf(fmaxf(b[k], b[k + 1]), b[k + 2])); // bottom row: 3 taps
        mx = fmaxf(mx, 0.0f);                                // implicit zero channel
        const float c = m[k + 1];
        op[k] = (c > mx) ? c : 0.0f;
    }
    *reinterpret_cast<float4*>(out + (long)idx * 4) = o;
}

extern "C" void kernel_launch(void* const* d_in, const int* in_sizes, int n_in,
                              void* d_out, int out_size, void* d_ws, size_t ws_size,
                              hipStream_t stream) {
    const float* x = (const float*)d_in[0];
    float* out = (float*)d_out;
    const int total4 = out_size / 4;  // 4 pixels per thread
    const int block = 256;
    const int grid = (total4 + block - 1) / block;
    nms2d_kernel<<<grid, block, 0, stream>>>(x, out, total4);
}

// Round 2
// 99.942 us; speedup vs baseline: 1.3944x; 1.3944x over previous
//
#include <hip/hip_runtime.h>

// NonMaximaSuppression2d: x shape (B=8, C=128, H=256, W=256) fp32.
// out[p] = x[p] if x[p] > max(0, 8 replicate-padded 3x3 neighbors) else 0.
// Reference's running max starts at 0 (center conv channel is all-zero),
// so negative x is always suppressed.
//
// Column-walking stencil: each thread owns a 4-wide x ROWS-tall column,
// rolling 3 rows (t/m/b) through registers. Amortized loads per output
// float4: 1.25 vector + 2.5 edge scalars (vs 3 + 6 for the naive version).

#define NMS_W 256
#define NMS_H 256
#define ROWS 8

__global__ __launch_bounds__(256) void nms2d_kernel(
    const float* __restrict__ x, float* __restrict__ out) {
    const int lane = threadIdx.x & 63;        // float4-segment along W (64/row)
    const int wid  = threadIdx.x >> 6;        // wave id in block: 0..3
    const int gid  = blockIdx.x;
    const int blocksPerPlane = (NMS_H / ROWS) / 4;   // 8
    const long plane = gid / blocksPerPlane;         // b*C + c
    const int  chunk = gid % blocksPerPlane;
    const int  row0  = (chunk * 4 + wid) * ROWS;

    const float* p = x   + plane * (long)(NMS_H * NMS_W);
    float*       q = out + plane * (long)(NMS_H * NMS_W);

    const int c0 = lane * 4;
    // Replicate padding via clamped column indices.
    const int cl = (c0 == 0) ? 0 : c0 - 1;
    const int cr = (c0 == NMS_W - 4) ? NMS_W - 1 : c0 + 4;

    float t[6], m[6], b[6];
    auto load6 = [&](int r, float* a) {
        const float* rp = p + (long)r * NMS_W;
        const float4 v = *reinterpret_cast<const float4*>(rp + c0);
        a[0] = rp[cl]; a[1] = v.x; a[2] = v.y; a[3] = v.z; a[4] = v.w; a[5] = rp[cr];
    };

    // Replicate padding on top edge: row -1 aliases row 0.
    load6(row0 == 0 ? 0 : row0 - 1, t);
    load6(row0, m);

#pragma unroll
    for (int r = 0; r < ROWS; ++r) {
        int rb = row0 + r + 1;
        if (rb > NMS_H - 1) rb = NMS_H - 1;   // bottom replicate
        load6(rb, b);

        float4 o;
        float* op = &o.x;
#pragma unroll
        for (int k = 0; k < 4; ++k) {
            // max over 8 non-center neighbors and the implicit 0 channel
            float mx = fmaxf(fmaxf(t[k], t[k + 1]), t[k + 2]);       // top 3
            mx = fmaxf(mx, fmaxf(m[k], m[k + 2]));                   // mid, skip center
            mx = fmaxf(mx, fmaxf(fmaxf(b[k], b[k + 1]), b[k + 2]));  // bottom 3
            mx = fmaxf(mx, 0.0f);
            const float c = m[k + 1];
            op[k] = (c > mx) ? c : 0.0f;
        }
        *reinterpret_cast<float4*>(q + (long)(row0 + r) * NMS_W + c0) = o;

#pragma unroll
        for (int k = 0; k < 6; ++k) { t[k] = m[k]; m[k] = b[k]; }
    }
}

extern "C" void kernel_launch(void* const* d_in, const int* in_sizes, int n_in,
                              void* d_out, int out_size, void* d_ws, size_t ws_size,
                              hipStream_t stream) {
    const float* x = (const float*)d_in[0];
    float* out = (float*)d_out;
    const int planes = out_size / (NMS_H * NMS_W);           // 1024
    const int grid = planes * ((NMS_H / ROWS) / 4);          // 8192 blocks
    nms2d_kernel<<<grid, 256, 0, stream>>>(x, out);
}